// Round 11
// baseline (108.820 us; speedup 1.0000x reference)
//
#include <hip/hip_runtime.h>
#include <math.h>
#include <stdint.h>

// SemiConv2d tropical conv: out[n,oc,h,w] = max_{ic,kh,kw} min(x_pad, K).
// R11: ONE fused kernel, no workspace, max reuse. Block = 1 output row x 96 w
// x ALL 32 oc. x window (3 rows x 32 ic) staged in LDS in two 16-ic phases
// (18.4KB); K staged once pair-packed (24.6KB, op_sel consumption -- R9-
// verified mapping). Inner loop: pure LDS + VALU, zero global/scalar loads.
// 768 blocks (3/CU, hp-fastest), 192 thr = 48 jj x 4 ocg. K LDS reads are
// 2-way per wave (free, m136). R2-R10 evidence: per-lane global-load designs
// all plateau at 45+-5us regardless of structure; this removes the per-ic
// global fetch + address tax entirely and drops 2 setup dispatches.

#define HH 96
#define WW 96
#define CIN 32
#define OCN 32
#define NEGH2 0xFC00FC00u

typedef _Float16 h2 __attribute__((ext_vector_type(2)));

// r.lo = min(x.lo, k.lo); r.hi = min(x.hi, k.lo)
__device__ __forceinline__ uint32_t pkmin_lo(uint32_t x, uint32_t k) {
    uint32_t d;
    asm("v_pk_min_f16 %0, %1, %2 op_sel:[0,0] op_sel_hi:[1,0]" : "=v"(d) : "v"(x), "v"(k));
    return d;
}
// r.lo = min(x.lo, k.hi); r.hi = min(x.hi, k.hi)
__device__ __forceinline__ uint32_t pkmin_hi(uint32_t x, uint32_t k) {
    uint32_t d;
    asm("v_pk_min_f16 %0, %1, %2 op_sel:[0,1] op_sel_hi:[1,1]" : "=v"(d) : "v"(x), "v"(k));
    return d;
}
__device__ __forceinline__ uint32_t pkmin_vv(uint32_t a, uint32_t b) {
    uint32_t d;
    asm("v_pk_min_f16 %0, %1, %2" : "=v"(d) : "v"(a), "v"(b));
    return d;
}
__device__ __forceinline__ uint32_t pkmax(uint32_t a, uint32_t b) {
    uint32_t d;
    asm("v_pk_max_f16 %0, %1, %2" : "=v"(d) : "v"(a), "v"(b));
    return d;
}
__device__ __forceinline__ uint32_t packh2(float lo, float hi) {
    h2 p = {(_Float16)lo, (_Float16)hi};
    return __builtin_bit_cast(uint32_t, p);
}

__global__ __launch_bounds__(192) void semiconv_fused(const float* __restrict__ x,
                                                      const float* __restrict__ kk,
                                                      float* __restrict__ out)
{
    // x tile: [r(3)][icl(16)][jj(48)] uint2 = 4-tap window pack  (18,432 B)
    __shared__ uint2 xls[3 * 16 * 48];
    // K: [ic*32+oc] -> 3 uint2: (k0,k1|k2,k3), (k4,k5|k6,k7), (k8,k8|0)  (24,576 B)
    __shared__ uint2 ksl[1024 * 3];

    const int tid = threadIdx.x;
    const int b   = blockIdx.x;
    const int h   = b % 96;            // h fastest -> XCD L2 locality on x
    const int n   = b / 96;
    const int jj  = tid % 48;          // w-pair
    const int ocg = tid / 48;          // 0..3
    const int oc0 = ocg * 8;

    // ---- stage K once (1024 cells / 192 threads) ----
    for (int c = tid; c < 1024; c += 192) {
        const int ic = c >> 5, oc = c & 31;
        const float* kb = kk + ((size_t)(oc * CIN + ic)) * 9;
        float k0 = kb[0], k1 = kb[1], k2 = kb[2], k3 = kb[3], k4 = kb[4];
        float k5 = kb[5], k6 = kb[6], k7 = kb[7], k8 = kb[8];
        ksl[c * 3 + 0] = make_uint2(packh2(k0, k1), packh2(k2, k3));
        ksl[c * 3 + 1] = make_uint2(packh2(k4, k5), packh2(k6, k7));
        ksl[c * 3 + 2] = make_uint2(packh2(k8, k8), 0u);
    }

    uint32_t acc[8];
#pragma unroll
    for (int i = 0; i < 8; ++i) acc[i] = NEGH2;

    for (int ph = 0; ph < 2; ++ph) {
        if (ph) __syncthreads();       // compute(ph0) done before restage
        // ---- stage x rows h-1..h+1 for ics ph*16..ph*16+15 ----
        for (int e = tid; e < 2304; e += 192) {
            const int r   = e / 768;          // 0..2
            const int icl = (e / 48) & 15;
            const int j   = e % 48;
            const int hr  = h - 1 + r;
            const bool hv = (hr >= 0) && (hr < HH);
            const float* row = x + ((size_t)(n * CIN + ph * 16 + icl) * HH + (hv ? hr : 0)) * WW;
            const int offm = (j > 0)  ? (2 * j - 2) : 0;
            const int offp = (j < 47) ? (2 * j + 2) : 0;
            float2 fm = *(const float2*)(row + offm);
            float2 f0 = *(const float2*)(row + 2 * j);
            float2 fp = *(const float2*)(row + offp);
            float a  = (hv && j > 0)  ? fm.y : -INFINITY;
            float bb = hv             ? f0.x : -INFINITY;
            float cc = hv             ? f0.y : -INFINITY;
            float dd = (hv && j < 47) ? fp.x : -INFINITY;
            xls[e] = make_uint2(packh2(a, bb), packh2(cc, dd));
        }
        __syncthreads();

#pragma unroll 4
        for (int icl = 0; icl < 16; ++icl) {
            uint2 w0 = xls[(0 * 16 + icl) * 48 + jj];
            uint2 w1 = xls[(1 * 16 + icl) * 48 + jj];
            uint2 w2 = xls[(2 * 16 + icl) * 48 + jj];
            uint32_t xt[3][3];
            xt[0][0] = w0.x; xt[0][1] = __builtin_amdgcn_alignbit(w0.y, w0.x, 16); xt[0][2] = w0.y;
            xt[1][0] = w1.x; xt[1][1] = __builtin_amdgcn_alignbit(w1.y, w1.x, 16); xt[1][2] = w1.y;
            xt[2][0] = w2.x; xt[2][1] = __builtin_amdgcn_alignbit(w2.y, w2.x, 16); xt[2][2] = w2.y;

            const int cbase = (ph * 16 + icl) * 32 + oc0;
#pragma unroll
            for (int i = 0; i < 8; ++i) {
                const int c = cbase + i;
                uint2 kd01 = ksl[c * 3 + 0];
                uint2 kd23 = ksl[c * 3 + 1];
                uint32_t kc = ksl[c * 3 + 2].x;
                uint32_t m0 = pkmin_lo(xt[0][0], kd01.x);
                uint32_t m1 = pkmin_hi(xt[0][1], kd01.x);
                uint32_t m2 = pkmin_lo(xt[0][2], kd01.y);
                uint32_t m3 = pkmin_hi(xt[1][0], kd01.y);
                uint32_t m4 = pkmin_lo(xt[1][1], kd23.x);
                uint32_t m5 = pkmin_hi(xt[1][2], kd23.x);
                uint32_t m6 = pkmin_lo(xt[2][0], kd23.y);
                uint32_t m7 = pkmin_hi(xt[2][1], kd23.y);
                uint32_t m8 = pkmin_vv(xt[2][2], kc);
                uint32_t t01 = pkmax(m0, m1), t23 = pkmax(m2, m3);
                uint32_t t45 = pkmax(m4, m5), t67 = pkmax(m6, m7);
                uint32_t tt  = pkmax(pkmax(t01, t23), pkmax(t45, t67));
                acc[i] = pkmax(acc[i], pkmax(tt, m8));
            }
        }
    }

#pragma unroll
    for (int i = 0; i < 8; ++i) {
        h2 a = __builtin_bit_cast(h2, acc[i]);
        float2 v = make_float2((float)a.x, (float)a.y);
        *(float2*)(out + (((size_t)(n * OCN + oc0 + i)) * HH + h) * WW + 2 * jj) = v;
    }
}

extern "C" void kernel_launch(void* const* d_in, const int* in_sizes, int n_in,
                              void* d_out, int out_size, void* d_ws, size_t ws_size,
                              hipStream_t stream) {
    const float* x  = (const float*)d_in[0];
    const float* kk = (const float*)d_in[1];
    float* out      = (float*)d_out;
    semiconv_fused<<<dim3(8 * 96), dim3(192), 0, stream>>>(x, kk, out);
}

// Round 12
// 101.939 us; speedup vs baseline: 1.0675x; 1.0675x over previous
//
#include <hip/hip_runtime.h>
#include <math.h>
#include <stdint.h>

// SemiConv2d tropical conv: out = max_{ic,kh,kw} min(x_pad, K). f16-packed.
// R12: R7's lean inner loop (3 uint2 loads + 3 alignbit + s-constraint K pk
// ops -- no LDS, no unpack) at DOUBLE residency: oc split C=2 -> grid
// 8n x 24hp x 16ocb = 3072 blocks = 9216 waves ~ 8 waves/SIMD
// (launch_bounds(192,8)). R5/R8 evidence: VALUBusy scales with waves
// (2.25w->36%, 4.5w->55%); R11 evidence: VALU stream ~2x pk-floor due to
// addressing -> keep the leanest loop of the series. K = 18 s_load dwords/ic
// (half of R7) -> scalar prefetch can pipeline. hp fastest and 24%8==0 =>
// XCD = hp%8: each XCD holds 3 hp-stripes (~1.8MB) reused by all 16 ocb.
// NOTE: ~55us of dur_us is fixed harness overhead (256MB ws poison fill).

#define HH 96
#define WW 96
#define CIN 32
#define OCN 32
#define XQ_ROWS 98
#define XQ_W 48
#define XQ_SLICE (XQ_ROWS * XQ_W)              // uint2 units per (n,ic) slice
#define XQ_TOTAL (256 * XQ_SLICE)              // uint2 elements
#define K2_TOTAL (16 * 32 * 2 * 9)             // uint32 elements
#define WS_NEED ((size_t)XQ_TOTAL * 8 + (size_t)K2_TOTAL * 4)
#define NEGH2 0xFC00FC00u

typedef _Float16 h2 __attribute__((ext_vector_type(2)));

__device__ __forceinline__ uint32_t pkmin_vs(uint32_t x, uint32_t k) {
    uint32_t d;
    asm("v_pk_min_f16 %0, %1, %2" : "=v"(d) : "v"(x), "s"(k));
    return d;
}
__device__ __forceinline__ uint32_t pkmax(uint32_t a, uint32_t b) {
    uint32_t d;
    asm("v_pk_max_f16 %0, %1, %2" : "=v"(d) : "v"(a), "v"(b));
    return d;
}
__device__ __forceinline__ uint32_t packh2(float lo, float hi) {
    h2 p = {(_Float16)lo, (_Float16)hi};
    return __builtin_bit_cast(uint32_t, p);
}

// xq[(s*98 + rowpad)*48 + j] = 4xf16 (x[2j-1],x[2j] | x[2j+1],x[2j+2]), s=n*32+ic
__global__ __launch_bounds__(256) void setup_xq(const float* __restrict__ x,
                                                uint2* __restrict__ xq) {
    int idx = blockIdx.x * 256 + threadIdx.x;   // over 256*98*48 = 1,204,224
    int j  = idx % XQ_W;
    int t  = idx / XQ_W;
    int hp = t % XQ_ROWS;
    int s  = t / XQ_ROWS;
    int h  = hp - 1;
    bool hv = (h >= 0) && (h < HH);
    const float* row = x + ((size_t)s * HH + (hv ? h : 0)) * WW;
    float a = (hv && j > 0)        ? row[2 * j - 1] : -INFINITY;
    float b = hv                   ? row[2 * j]     : -INFINITY;
    float c = hv                   ? row[2 * j + 1] : -INFINITY;
    float d = (hv && j < XQ_W - 1) ? row[2 * j + 2] : -INFINITY;
    uint2 v;
    v.x = packh2(a, b);
    v.y = packh2(c, d);
    xq[idx] = v;
}

// k2[ocb(16)][ic(32)][oc2(2)][9] duplicated f16 pairs
__global__ __launch_bounds__(256) void setup_k(const float* __restrict__ kk,
                                               uint32_t* __restrict__ k2) {
    int idx = blockIdx.x * 256 + threadIdx.x;   // over 9216
    int tap = idx % 9;
    int oc2 = (idx / 9) % 2;
    int ic  = (idx / 18) % CIN;
    int ocb = idx / (18 * CIN);
    float v = kk[(((ocb * 2 + oc2) * CIN) + ic) * 9 + tap];
    k2[idx] = packh2(v, v);
}

__global__ __launch_bounds__(192, 8) void semiconv_f16(const uint2* __restrict__ xq,
                                                       const uint32_t* __restrict__ k2,
                                                       float* __restrict__ out) {
    const int tid = threadIdx.x;
    const int jj = tid % 48;          // w-pair 0..47
    const int hr = tid / 48;          // 0..3
    const int b  = blockIdx.x;
    const int hp  = b % 24;           // hp FASTEST; 24%8==0 => XCD = hp%8
    const int t   = b / 24;
    const int ocb = t & 15;           // oc-chunk of 2
    const int n   = t >> 4;
    const int h   = hp * 4 + hr;      // one output row per thread

    // padded row r = x row (h-1+r); output h uses padded rows h, h+1, h+2
    const uint2* xp = xq + ((size_t)(n * CIN) * XQ_ROWS + h) * XQ_W + jj;
    const uint32_t* kp = k2 + (size_t)ocb * CIN * 18;

    uint32_t acc[2] = {NEGH2, NEGH2};

    for (int ic0 = 0; ic0 < CIN; ic0 += 2) {
        uint2 q[2][3];
#pragma unroll
        for (int u = 0; u < 2; ++u)
#pragma unroll
            for (int r = 0; r < 3; ++r)
                q[u][r] = xp[(size_t)u * XQ_SLICE + r * XQ_W];

#pragma unroll
        for (int u = 0; u < 2; ++u) {
            uint32_t tap[9];
#pragma unroll
            for (int r = 0; r < 3; ++r) {
                tap[r * 3 + 0] = q[u][r].x;
                tap[r * 3 + 1] = __builtin_amdgcn_alignbit(q[u][r].y, q[u][r].x, 16);
                tap[r * 3 + 2] = q[u][r].y;
            }
            const uint32_t* kq0 = kp + (ic0 + u) * 18;
#pragma unroll
            for (int oc = 0; oc < 2; ++oc) {
                const uint32_t* kq = kq0 + oc * 9;       // uniform -> s_load
                uint32_t m0 = pkmin_vs(tap[0], kq[0]);
                uint32_t m1 = pkmin_vs(tap[1], kq[1]);
                uint32_t m2 = pkmin_vs(tap[2], kq[2]);
                uint32_t m3 = pkmin_vs(tap[3], kq[3]);
                uint32_t m4 = pkmin_vs(tap[4], kq[4]);
                uint32_t m5 = pkmin_vs(tap[5], kq[5]);
                uint32_t m6 = pkmin_vs(tap[6], kq[6]);
                uint32_t m7 = pkmin_vs(tap[7], kq[7]);
                uint32_t m8 = pkmin_vs(tap[8], kq[8]);
                uint32_t t01 = pkmax(m0, m1), t23 = pkmax(m2, m3);
                uint32_t t45 = pkmax(m4, m5), t67 = pkmax(m6, m7);
                uint32_t tt  = pkmax(pkmax(t01, t23), pkmax(t45, t67));
                acc[oc] = pkmax(acc[oc], pkmax(tt, m8));
            }
        }
        xp += 2 * XQ_SLICE;
    }

#pragma unroll
    for (int oc = 0; oc < 2; ++oc) {
        h2 a = __builtin_bit_cast(h2, acc[oc]);
        float2 v = make_float2((float)a.x, (float)a.y);
        *(float2*)(out + (((size_t)(n * OCN + ocb * 2 + oc)) * HH + h) * WW + 2 * jj) = v;
    }
}

// ---------- f32 fallback if ws is too small ----------
#define NEGINF (-INFINITY)
__global__ __launch_bounds__(192, 8) void semiconv2d_f32(
    const float* __restrict__ x, const float* __restrict__ kk, float* __restrict__ out)
{
    const int tid = threadIdx.x;
    const int w  = tid % WW;
    const int hr = tid / WW;
    const int b   = blockIdx.x;
    const int ocb = b & 7;
    const int hp  = (b >> 3) % 48;
    const int n   = (b >> 3) / 48;
    const int h   = hp * 2 + hr;
    const int oc0 = ocb * 4;
    float a0[4], a1[4], a2[4];
#pragma unroll
    for (int i = 0; i < 4; ++i) { a0[i] = NEGINF; a1[i] = NEGINF; a2[i] = NEGINF; }
    const bool vm = (h > 0), vp = (h < HH - 1);
    const int hm  = vm ? h - 1 : h;
    const int hpl = vp ? h + 1 : h;
    const int cm  = (w > 0) ? -1 : 0;
    const int cp  = (w < WW - 1) ? 1 : 0;
    const float* rm = x + ((size_t)(n * CIN) * HH + hm)  * WW + w;
    const float* r1 = x + ((size_t)(n * CIN) * HH + h)   * WW + w;
    const float* rp = x + ((size_t)(n * CIN) * HH + hpl) * WW + w;
#pragma unroll 2
    for (int ic = 0; ic < CIN; ++ic) {
        float r00 = vm ? rm[cm] : NEGINF, r01 = vm ? rm[0] : NEGINF, r02 = vm ? rm[cp] : NEGINF;
        float r10 = r1[cm], r11 = r1[0], r12 = r1[cp];
        float r20 = vp ? rp[cm] : NEGINF, r21 = vp ? rp[0] : NEGINF, r22 = vp ? rp[cp] : NEGINF;
#pragma unroll
        for (int oc = 0; oc < 4; ++oc) {
            const float* kq = kk + (size_t)(((oc0 + oc) * CIN + ic)) * 9;
            a0[oc] = fmaxf(fmaxf(a0[oc], fminf(r00, kq[0])), fmaxf(fminf(r10, kq[3]), fminf(r20, kq[6])));
            a1[oc] = fmaxf(fmaxf(a1[oc], fminf(r01, kq[1])), fmaxf(fminf(r11, kq[4]), fminf(r21, kq[7])));
            a2[oc] = fmaxf(fmaxf(a2[oc], fminf(r02, kq[2])), fmaxf(fminf(r12, kq[5]), fminf(r22, kq[8])));
        }
        rm += HH * WW; r1 += HH * WW; rp += HH * WW;
    }
#pragma unroll
    for (int oc = 0; oc < 4; ++oc) {
        float v0 = (w > 0)      ? a0[oc] : NEGINF;
        float v2 = (w < WW - 1) ? a2[oc] : NEGINF;
        out[(((size_t)(n * OCN + oc0 + oc)) * HH + h) * WW + w] = fmaxf(fmaxf(v0, a1[oc]), v2);
    }
}

extern "C" void kernel_launch(void* const* d_in, const int* in_sizes, int n_in,
                              void* d_out, int out_size, void* d_ws, size_t ws_size,
                              hipStream_t stream) {
    const float* x  = (const float*)d_in[0];
    const float* kk = (const float*)d_in[1];
    float* out      = (float*)d_out;
    if (ws_size >= WS_NEED) {
        uint2* xq    = (uint2*)d_ws;
        uint32_t* k2 = (uint32_t*)(xq + XQ_TOTAL);
        setup_xq<<<dim3(XQ_TOTAL / 256), dim3(256), 0, stream>>>(x, xq);
        setup_k<<<dim3(K2_TOTAL / 256), dim3(256), 0, stream>>>(kk, k2);
        semiconv_f16<<<dim3(8 * 16 * 24), dim3(192), 0, stream>>>(xq, k2, out);
    } else {
        semiconv2d_f32<<<dim3(8 * 48 * 8), dim3(192), 0, stream>>>(x, kk, out);
    }
}

// Round 13
// 101.563 us; speedup vs baseline: 1.0714x; 1.0037x over previous
//
#include <hip/hip_runtime.h>
#include <math.h>
#include <stdint.h>

// SemiConv2d tropical conv: out = max_{ic,kh,kw} min(x_pad, K). f16-packed.
// R13: EARLY EXIT on sorted taps. min(x,k)<=k, so once acc >= k for all
// remaining taps the result is final. Taps sorted descending by k per oc
// (setup_tap); main loop scans 4-tap chunks and breaks when every lane's
// both packed halves >= next chunk's k (max remaining). Order stats: per-
// output crossing ~16 taps, wave-coherent exit ~40-48 of 288 => ~6x fewer
// taps. Per tap: 1 dwordx2 (xq ws, uniform s-offset + fixed lane voffset),
// 1 alignbit (s-shift picks kw parity), 1 pk_min (s-k), tree max. Chunk
// table double-buffered (s_load prefetch). Exact: skipped taps provably
// non-contributing -> absmax identical to R12 (0.015625).
// R2-R12 evidence: 8 structural variants all pinned at main 38-53us ->
// conserved taps x per-tap cost; only work reduction is left.

#define HH 96
#define WW 96
#define CIN 32
#define OCN 32
#define XQ_ROWS 98
#define XQ_W 48
#define XQ_SLICE (XQ_ROWS * XQ_W)              // uint2 units per (n,ic) slice
#define XQ_TOTAL (256 * XQ_SLICE)              // uint2 elements
#define TB_TOTAL (32 * 288)                    // uint4 entries
#define WS_NEED ((size_t)XQ_TOTAL * 8 + (size_t)TB_TOTAL * 16)
#define NEGH2 0xFC00FC00u

typedef _Float16 h2 __attribute__((ext_vector_type(2)));
typedef uint32_t u2a4 __attribute__((ext_vector_type(2), aligned(4)));

__device__ __forceinline__ uint32_t pkmin_vs(uint32_t x, uint32_t k) {
    uint32_t d;
    asm("v_pk_min_f16 %0, %1, %2" : "=v"(d) : "v"(x), "s"(k));
    return d;
}
__device__ __forceinline__ uint32_t pkmin_vv(uint32_t a, uint32_t b) {
    uint32_t d;
    asm("v_pk_min_f16 %0, %1, %2" : "=v"(d) : "v"(a), "v"(b));
    return d;
}
__device__ __forceinline__ uint32_t pkmax(uint32_t a, uint32_t b) {
    uint32_t d;
    asm("v_pk_max_f16 %0, %1, %2" : "=v"(d) : "v"(a), "v"(b));
    return d;
}
__device__ __forceinline__ uint32_t packh2(float lo, float hi) {
    h2 p = {(_Float16)lo, (_Float16)hi};
    return __builtin_bit_cast(uint32_t, p);
}

// xq[(s*98 + rowpad)*48 + j] = 4xf16 (x[2j-1],x[2j] | x[2j+1],x[2j+2]), s=n*32+ic
__global__ __launch_bounds__(256) void setup_xq(const float* __restrict__ x,
                                                uint2* __restrict__ xq) {
    int idx = blockIdx.x * 256 + threadIdx.x;   // over 256*98*48 = 1,204,224
    int j  = idx % XQ_W;
    int t  = idx / XQ_W;
    int hp = t % XQ_ROWS;
    int s  = t / XQ_ROWS;
    int h  = hp - 1;
    bool hv = (h >= 0) && (h < HH);
    const float* row = x + ((size_t)s * HH + (hv ? h : 0)) * WW;
    float a = (hv && j > 0)        ? row[2 * j - 1] : -INFINITY;
    float b = hv                   ? row[2 * j]     : -INFINITY;
    float c = hv                   ? row[2 * j + 1] : -INFINITY;
    float d = (hv && j < XQ_W - 1) ? row[2 * j + 2] : -INFINITY;
    uint2 v;
    v.x = packh2(a, b);
    v.y = packh2(c, d);
    xq[idx] = v;
}

// per-oc tap table sorted by k descending: entry {k_dup_f16, byte_off, shift, 0}
__global__ void setup_tap(const float* __restrict__ kk, uint4* __restrict__ tbl) {
    __shared__ float ks[288];
    const int oc = blockIdx.x;                  // 32 blocks
    const int t  = threadIdx.x;                 // 288 threads
    float k = kk[oc * 288 + t];
    ks[t] = k;
    __syncthreads();
    int rank = 0;
    for (int s = 0; s < 288; ++s) {
        float kv = ks[s];
        rank += (kv > k) || (kv == k && s < t);
    }
    const int ic = t / 9, tap = t % 9, dh = tap / 3, dw = tap % 3;
    uint32_t off = (uint32_t)(ic * XQ_ROWS + dh) * (XQ_W * 8) + (dw == 2 ? 4u : 0u);
    uint32_t sh  = (dw == 1) ? 16u : 0u;
    tbl[oc * 288 + rank] = make_uint4(packh2(k, k), off, sh, 0u);
}

__device__ __forceinline__ uint32_t tapval(const char* xb, int vbyte, uint4 e) {
    u2a4 q = *(const u2a4*)(xb + e.y + (uint32_t)vbyte);
    uint32_t v = __builtin_amdgcn_alignbit(q.y, q.x, e.z);
    return pkmin_vs(v, e.x);
}

__global__ __launch_bounds__(192, 8) void semiconv_ee(const char* __restrict__ xqb,
                                                      const uint4* __restrict__ tbl,
                                                      float* __restrict__ out) {
    const int tid = threadIdx.x;
    const int jj = tid % 48;          // w-pair 0..47
    const int hr = tid / 48;          // 0..3
    const int b  = blockIdx.x;
    const int hp = b % 24;            // hp FASTEST; XCD = hp%8 -> L2 locality
    const int t  = b / 24;
    const int oc = t & 31;
    const int n  = t >> 5;
    const int h  = hp * 4 + hr;       // one output row per thread (2 w)

    const char* xb = xqb + (size_t)n * CIN * XQ_SLICE * 8;
    const int vbyte = (h * XQ_W + jj) * 8;
    const uint4* tb = tbl + oc * 288;

    uint32_t acc = NEGH2;
    uint4 e0 = tb[0], e1 = tb[1], e2 = tb[2], e3 = tb[3];

    for (int c = 0; c < 72; ++c) {
        uint4 f0, f1, f2, f3;
        if (c < 71) {                 // prefetch next chunk (uniform -> s_load)
            const uint4* nb = tb + 4 * (c + 1);
            f0 = nb[0]; f1 = nb[1]; f2 = nb[2]; f3 = nb[3];
        }
        uint32_t m0 = tapval(xb, vbyte, e0);
        uint32_t m1 = tapval(xb, vbyte, e1);
        uint32_t m2 = tapval(xb, vbyte, e2);
        uint32_t m3 = tapval(xb, vbyte, e3);
        acc = pkmax(acc, pkmax(pkmax(m0, m1), pkmax(m2, m3)));

        if (c < 71) {
            // done iff min(acc.lo, acc.hi) >= next k (max of remaining)
            uint32_t sw = __builtin_amdgcn_alignbit(acc, acc, 16);
            uint32_t mn = pkmin_vv(acc, sw);
            h2 a  = __builtin_bit_cast(h2, mn);
            h2 kn = __builtin_bit_cast(h2, f0.x);
            if (__all((float)a.x >= (float)kn.x)) break;
            e0 = f0; e1 = f1; e2 = f2; e3 = f3;
        }
    }

    h2 a = __builtin_bit_cast(h2, acc);
    float2 v = make_float2((float)a.x, (float)a.y);
    *(float2*)(out + (((size_t)(n * OCN + oc)) * HH + h) * WW + 2 * jj) = v;
}

// ---------- f32 fallback if ws is too small ----------
#define NEGINF (-INFINITY)
__global__ __launch_bounds__(192, 8) void semiconv2d_f32(
    const float* __restrict__ x, const float* __restrict__ kk, float* __restrict__ out)
{
    const int tid = threadIdx.x;
    const int w  = tid % WW;
    const int hr = tid / WW;
    const int b   = blockIdx.x;
    const int ocb = b & 7;
    const int hp  = (b >> 3) % 48;
    const int n   = (b >> 3) / 48;
    const int h   = hp * 2 + hr;
    const int oc0 = ocb * 4;
    float a0[4], a1[4], a2[4];
#pragma unroll
    for (int i = 0; i < 4; ++i) { a0[i] = NEGINF; a1[i] = NEGINF; a2[i] = NEGINF; }
    const bool vm = (h > 0), vp = (h < HH - 1);
    const int hm  = vm ? h - 1 : h;
    const int hpl = vp ? h + 1 : h;
    const int cm  = (w > 0) ? -1 : 0;
    const int cp  = (w < WW - 1) ? 1 : 0;
    const float* rm = x + ((size_t)(n * CIN) * HH + hm)  * WW + w;
    const float* r1 = x + ((size_t)(n * CIN) * HH + h)   * WW + w;
    const float* rp = x + ((size_t)(n * CIN) * HH + hpl) * WW + w;
#pragma unroll 2
    for (int ic = 0; ic < CIN; ++ic) {
        float r00 = vm ? rm[cm] : NEGINF, r01 = vm ? rm[0] : NEGINF, r02 = vm ? rm[cp] : NEGINF;
        float r10 = r1[cm], r11 = r1[0], r12 = r1[cp];
        float r20 = vp ? rp[cm] : NEGINF, r21 = vp ? rp[0] : NEGINF, r22 = vp ? rp[cp] : NEGINF;
#pragma unroll
        for (int oc = 0; oc < 4; ++oc) {
            const float* kq = kk + (size_t)(((oc0 + oc) * CIN + ic)) * 9;
            a0[oc] = fmaxf(fmaxf(a0[oc], fminf(r00, kq[0])), fmaxf(fminf(r10, kq[3]), fminf(r20, kq[6])));
            a1[oc] = fmaxf(fmaxf(a1[oc], fminf(r01, kq[1])), fmaxf(fminf(r11, kq[4]), fminf(r21, kq[7])));
            a2[oc] = fmaxf(fmaxf(a2[oc], fminf(r02, kq[2])), fmaxf(fminf(r12, kq[5]), fminf(r22, kq[8])));
        }
        rm += HH * WW; r1 += HH * WW; rp += HH * WW;
    }
#pragma unroll
    for (int oc = 0; oc < 4; ++oc) {
        float v0 = (w > 0)      ? a0[oc] : NEGINF;
        float v2 = (w < WW - 1) ? a2[oc] : NEGINF;
        out[(((size_t)(n * OCN + oc0 + oc)) * HH + h) * WW + w] = fmaxf(fmaxf(v0, a1[oc]), v2);
    }
}

extern "C" void kernel_launch(void* const* d_in, const int* in_sizes, int n_in,
                              void* d_out, int out_size, void* d_ws, size_t ws_size,
                              hipStream_t stream) {
    const float* x  = (const float*)d_in[0];
    const float* kk = (const float*)d_in[1];
    float* out      = (float*)d_out;
    if (ws_size >= WS_NEED) {
        uint2* xq  = (uint2*)d_ws;
        uint4* tbl = (uint4*)((char*)d_ws + (size_t)XQ_TOTAL * 8);
        setup_xq<<<dim3(XQ_TOTAL / 256), dim3(256), 0, stream>>>(x, xq);
        setup_tap<<<dim3(32), dim3(288), 0, stream>>>(kk, tbl);
        semiconv_ee<<<dim3(8 * 32 * 24), dim3(192), 0, stream>>>(
            (const char*)xq, tbl, out);
    } else {
        semiconv2d_f32<<<dim3(8 * 48 * 8), dim3(192), 0, stream>>>(x, kk, out);
    }
}